// Round 1
// baseline (186.101 us; speedup 1.0000x reference)
//
#include <hip/hip_runtime.h>
#include <hip/hip_bf16.h>
#include <math.h>

// GAT layer: B=8, N=2048, F_IN=F_OUT=64
// out = elu( softmax(mask(leaky_relu(e1_i + e2_j), adj)) @ Wh ),
//   Wh = h @ W^T, e1 = Wh@a1, e2 = Wh@a2.
// Softmax without max-subtraction: scores are O(1) (|e1+e2| < ~2), masked
// entries exp(-9e15) underflow to 0 exactly — matches reference numerics.

#define NN 2048
#define BB 8
#define FF 64
#define ALPHA 0.2f

// ---------------- Kernel 1: Wh, e1, e2 ----------------
// 256 blocks x 256 threads; each wave computes 16 rows, lane o = output comp.
__global__ __launch_bounds__(256) void k_wh(
    const float* __restrict__ h, const float* __restrict__ W,
    const float* __restrict__ a, float* __restrict__ Wh,
    float* __restrict__ e1, float* __restrict__ e2) {
  __shared__ float Wt[64][65];   // W transposed, padded: conflict-free r/w
  __shared__ float hs[4][64];    // one h row per wave
  const int t = threadIdx.x, lane = t & 63, w = t >> 6;

  // stage W transposed: idx = o*64+f ; lane writes Wt[lane][w+4q] -> bank-free
  #pragma unroll
  for (int q = 0; q < 16; ++q) {
    int idx = t + 256 * q;
    Wt[idx & 63][idx >> 6] = W[idx];
  }
  const float a1v = a[lane], a2v = a[64 + lane];
  __syncthreads();

  const long rowBase = (long)blockIdx.x * 64 + (long)w * 16;
  for (int rr = 0; rr < 16; ++rr) {
    const long row = rowBase + rr;
    hs[w][lane] = h[row * 64 + lane];   // wave-local; compiler inserts lgkmcnt
    float acc = 0.f;
    #pragma unroll
    for (int f = 0; f < 64; ++f)
      acc = fmaf(hs[w][f], Wt[f][lane], acc);
    Wh[row * 64 + lane] = acc;
    float s1 = acc * a1v, s2 = acc * a2v;
    #pragma unroll
    for (int m = 1; m < 64; m <<= 1) {
      s1 += __shfl_xor(s1, m);
      s2 += __shfl_xor(s2, m);
    }
    if (lane == 0) { e1[row] = s1; e2[row] = s2; }
  }
}

// ---------------- Kernel 2: fused attention ----------------
// Grid (N/64, B). Block 256 thr. TI=TJ=64. Double-buffered LDS, 1 barrier/tile.
// Per thread: 4x4 micro-tile of (row i, comp o); P generated on the fly.
__global__ __launch_bounds__(256) void k_attn(
    const float* __restrict__ adj, const float* __restrict__ Wh,
    const float* __restrict__ e1g, const float* __restrict__ e2g,
    float* __restrict__ out) {
  __shared__ float Whs[2][64][64];   // [buf][j][o]  32 KB
  __shared__ float Pts[2][64][68];   // [buf][j][i] padded (float4-aligned)
  __shared__ float e1s[64];
  __shared__ float ls[64];

  const int t = threadIdx.x, lane = t & 63, w = t >> 6;
  const int b = blockIdx.y;
  const int i0 = blockIdx.x * 64;
  const long bN = (long)b * NN;

  if (t < 64) e1s[t] = e1g[bN + i0 + t];

  float acc[4][4];
  #pragma unroll
  for (int x = 0; x < 4; ++x)
    #pragma unroll
    for (int y = 0; y < 4; ++y) acc[x][y] = 0.f;
  float myps[16];
  #pragma unroll
  for (int r = 0; r < 16; ++r) myps[r] = 0.f;

  const int ti = t >> 4, to = t & 15;   // GEMM mapping: rows 4*ti.., cols 4*to..

  float4 whr[4];
  float adjr[16];
  float e2v = 0.f;

  auto prefetch = [&](int jt) {
    const int j0 = jt * 64;
    #pragma unroll
    for (int q = 0; q < 4; ++q) {
      const int idx = t + 256 * q;           // 0..1023 float4s of the tile
      const int jj = idx >> 4, c = (idx & 15) << 2;
      whr[q] = *(const float4*)&Wh[(bN + j0 + jj) * 64 + c];
    }
    e2v = e2g[bN + j0 + lane];
    #pragma unroll
    for (int r = 0; r < 16; ++r) {
      const int il = w * 16 + r;
      adjr[r] = adj[(long)(i0 + il) * NN + j0 + lane];
    }
  };

  auto writeback = [&](int buf) {
    #pragma unroll
    for (int q = 0; q < 4; ++q) {
      const int idx = t + 256 * q;
      const int jj = idx >> 4, c = (idx & 15) << 2;
      *(float4*)&Whs[buf][jj][c] = whr[q];
    }
    #pragma unroll
    for (int r = 0; r < 16; ++r) {
      const int il = w * 16 + r;
      const float tv = e1s[il] + e2v;
      const float lr = fmaxf(tv, 0.f) + ALPHA * fminf(tv, 0.f);
      const float pv = (adjr[r] > 0.f) ? __expf(lr) : 0.f;
      Pts[buf][lane][il] = pv;
      myps[r] += pv;
    }
  };

  __syncthreads();          // e1s visible
  prefetch(0);
  writeback(0);
  __syncthreads();

  for (int jt = 0; jt < 32; ++jt) {
    const int cur = jt & 1;
    if (jt + 1 < 32) prefetch(jt + 1);   // globals in flight during GEMM
    #pragma unroll 8
    for (int k = 0; k < 64; ++k) {
      const float4 pv = *(const float4*)&Pts[cur][k][ti << 2];
      const float4 wv = *(const float4*)&Whs[cur][k][to << 2];
      acc[0][0] = fmaf(pv.x, wv.x, acc[0][0]);
      acc[0][1] = fmaf(pv.x, wv.y, acc[0][1]);
      acc[0][2] = fmaf(pv.x, wv.z, acc[0][2]);
      acc[0][3] = fmaf(pv.x, wv.w, acc[0][3]);
      acc[1][0] = fmaf(pv.y, wv.x, acc[1][0]);
      acc[1][1] = fmaf(pv.y, wv.y, acc[1][1]);
      acc[1][2] = fmaf(pv.y, wv.z, acc[1][2]);
      acc[1][3] = fmaf(pv.y, wv.w, acc[1][3]);
      acc[2][0] = fmaf(pv.z, wv.x, acc[2][0]);
      acc[2][1] = fmaf(pv.z, wv.y, acc[2][1]);
      acc[2][2] = fmaf(pv.z, wv.z, acc[2][2]);
      acc[2][3] = fmaf(pv.z, wv.w, acc[2][3]);
      acc[3][0] = fmaf(pv.w, wv.x, acc[3][0]);
      acc[3][1] = fmaf(pv.w, wv.y, acc[3][1]);
      acc[3][2] = fmaf(pv.w, wv.z, acc[3][2]);
      acc[3][3] = fmaf(pv.w, wv.w, acc[3][3]);
    }
    if (jt + 1 < 32) writeback(cur ^ 1);
    __syncthreads();
  }

  // row sums (per-thread partials -> wave butterfly, once)
  #pragma unroll
  for (int r = 0; r < 16; ++r) {
    float v = myps[r];
    #pragma unroll
    for (int m = 1; m < 64; m <<= 1) v += __shfl_xor(v, m);
    if (lane == 0) ls[w * 16 + r] = v;
  }
  __syncthreads();

  // epilogue: normalize, ELU, store
  #pragma unroll
  for (int x = 0; x < 4; ++x) {
    const int il = (ti << 2) + x;
    const float lsum = ls[il];
    float4 o;
    float v;
    v = acc[x][0] / lsum; o.x = v > 0.f ? v : expm1f(v);
    v = acc[x][1] / lsum; o.y = v > 0.f ? v : expm1f(v);
    v = acc[x][2] / lsum; o.z = v > 0.f ? v : expm1f(v);
    v = acc[x][3] / lsum; o.w = v > 0.f ? v : expm1f(v);
    *(float4*)&out[(bN + i0 + il) * 64 + (to << 2)] = o;
  }
}

extern "C" void kernel_launch(void* const* d_in, const int* in_sizes, int n_in,
                              void* d_out, int out_size, void* d_ws, size_t ws_size,
                              hipStream_t stream) {
  (void)in_sizes; (void)n_in; (void)out_size; (void)ws_size;
  const float* h   = (const float*)d_in[0];
  const float* adj = (const float*)d_in[1];
  const float* W   = (const float*)d_in[2];
  const float* a   = (const float*)d_in[3];
  float* outp = (float*)d_out;

  float* ws = (float*)d_ws;
  float* Wh = ws;                       // B*N*64 = 1048576 floats
  float* e1 = Wh + (size_t)BB * NN * FF;
  float* e2 = e1 + (size_t)BB * NN;     // total ~4.33 MB of d_ws

  k_wh<<<256, 256, 0, stream>>>(h, W, a, Wh, e1, e2);
  k_attn<<<dim3(NN / 64, BB), 256, 0, stream>>>(adj, Wh, e1, e2, outp);
}

// Round 2
// 104.444 us; speedup vs baseline: 1.7818x; 1.7818x over previous
//
#include <hip/hip_runtime.h>
#include <hip/hip_bf16.h>
#include <math.h>

// GAT layer B=8, N=2048, F=64 on gfx950.
// Round 2: PV GEMM on bf16 MFMA (16x16x32), adj->bitmask prepass,
// Wh produced transposed-bf16 [B,64,N] so B-fragments are contiguous b128.
// Softmax without max-subtraction (scores O(1), masked p == exact 0).

#define NN 2048
#define BB 8
#define ALPHA 0.2f

typedef __attribute__((ext_vector_type(8))) short s8v;   // 8 bf16 = 4 VGPRs
typedef __attribute__((ext_vector_type(4))) float f4v;   // MFMA acc

static __device__ __forceinline__ unsigned short bf16rne(float x) {
  union { float f; unsigned u; } c; c.f = x;
  unsigned r = c.u + 0x7FFFu + ((c.u >> 16) & 1u);
  return (unsigned short)(r >> 16);
}

// ---------------- Kernel A: adj -> bitmask [N][N/32] ----------------
__global__ __launch_bounds__(256) void k_adj(const float* __restrict__ adj,
                                             unsigned* __restrict__ adjw) {
  const int row = blockIdx.x;
  const int w = threadIdx.x >> 6, lane = threadIdx.x & 63;
  #pragma unroll
  for (int it = 0; it < 8; ++it) {
    const int j = it * 256 + w * 64 + lane;
    unsigned long long m = __ballot(adj[(size_t)row * NN + j] > 0.f);
    if (lane < 2)
      adjw[row * (NN / 32) + it * 8 + w * 2 + lane] = (unsigned)(m >> (32 * lane));
  }
}

// ---------------- Kernel B: Wh (bf16, transposed [B,64,N]) + e1,e2 ----------------
// 256 blocks x 256 thr; block = 64 rows (one b). lane = output comp o.
__global__ __launch_bounds__(256) void k_wh(
    const float* __restrict__ h, const float* __restrict__ W,
    const float* __restrict__ a, unsigned short* __restrict__ whtg,
    float* __restrict__ e1, float* __restrict__ e2) {
  __shared__ __align__(16) float hsAll[64][68];          // rows of h, padded
  __shared__ __align__(16) unsigned short Ws[64][72];    // [o][row] bf16, 144B rows
  const int t = threadIdx.x, lane = t & 63, w = t >> 6;
  const int rowBase = blockIdx.x * 64;
  const int b = rowBase >> 11, n0 = rowBase & (NN - 1);

  // W row `lane` in registers: wr[f] = W[o=lane][f]
  float wr[64];
  #pragma unroll
  for (int k = 0; k < 16; ++k)
    *(f4v*)&wr[k * 4] = *(const f4v*)&W[lane * 64 + k * 4];

  #pragma unroll
  for (int qq = 0; qq < 4; ++qq) {
    const int f4i = t + 256 * qq;                 // 1024 float4s
    const int r = f4i >> 4, c = (f4i & 15) * 4;
    *(f4v*)&hsAll[r][c] = *(const f4v*)&h[(size_t)(rowBase + r) * 64 + c];
  }
  const float a1v = a[lane], a2v = a[64 + lane];
  __syncthreads();

  #pragma unroll
  for (int g = 0; g < 4; ++g) {
    const int r0 = w * 16 + g * 4;
    float ac0 = 0.f, ac1 = 0.f, ac2 = 0.f, ac3 = 0.f;
    #pragma unroll
    for (int f4i = 0; f4i < 16; ++f4i) {
      const f4v h0 = *(const f4v*)&hsAll[r0 + 0][f4i * 4];
      const f4v h1 = *(const f4v*)&hsAll[r0 + 1][f4i * 4];
      const f4v h2 = *(const f4v*)&hsAll[r0 + 2][f4i * 4];
      const f4v h3 = *(const f4v*)&hsAll[r0 + 3][f4i * 4];
      #pragma unroll
      for (int x = 0; x < 4; ++x) {
        const float wv = wr[f4i * 4 + x];
        ac0 = fmaf(h0[x], wv, ac0);
        ac1 = fmaf(h1[x], wv, ac1);
        ac2 = fmaf(h2[x], wv, ac2);
        ac3 = fmaf(h3[x], wv, ac3);
      }
    }
    Ws[lane][r0 + 0] = bf16rne(ac0);
    Ws[lane][r0 + 1] = bf16rne(ac1);
    Ws[lane][r0 + 2] = bf16rne(ac2);
    Ws[lane][r0 + 3] = bf16rne(ac3);
    float s10 = ac0 * a1v, s20 = ac0 * a2v;
    float s11 = ac1 * a1v, s21 = ac1 * a2v;
    float s12 = ac2 * a1v, s22 = ac2 * a2v;
    float s13 = ac3 * a1v, s23 = ac3 * a2v;
    #pragma unroll
    for (int m = 1; m < 64; m <<= 1) {
      s10 += __shfl_xor(s10, m); s20 += __shfl_xor(s20, m);
      s11 += __shfl_xor(s11, m); s21 += __shfl_xor(s21, m);
      s12 += __shfl_xor(s12, m); s22 += __shfl_xor(s22, m);
      s13 += __shfl_xor(s13, m); s23 += __shfl_xor(s23, m);
    }
    if (lane == 0) {
      e1[rowBase + r0 + 0] = s10; e2[rowBase + r0 + 0] = s20;
      e1[rowBase + r0 + 1] = s11; e2[rowBase + r0 + 1] = s21;
      e1[rowBase + r0 + 2] = s12; e2[rowBase + r0 + 2] = s22;
      e1[rowBase + r0 + 3] = s13; e2[rowBase + r0 + 3] = s23;
    }
  }
  __syncthreads();

  // transposed coalesced store: whtg[b*64+o][n0 + seg*16 .. +15]
  const int o = t >> 2, seg = t & 3;
  const s8v v0 = *(const s8v*)&Ws[o][seg * 16];
  const s8v v1 = *(const s8v*)&Ws[o][seg * 16 + 8];
  unsigned short* dst = whtg + (size_t)(b * 64 + o) * NN + n0 + seg * 16;
  *(s8v*)dst = v0;
  *(s8v*)(dst + 8) = v1;
}

// ---------------- Kernel C: fused attention, MFMA PV ----------------
// Grid (N/32, B) = (64, 8) = 512 blocks, 256 thr. i-tile 32, KT=64, dbuf LDS.
__global__ __launch_bounds__(256) void k_attn(
    const unsigned* __restrict__ adjw, const unsigned short* __restrict__ whtg,
    const float* __restrict__ e1g, const float* __restrict__ e2g,
    float* __restrict__ out) {
  __shared__ __align__(16) unsigned short Whs[2][64][72];  // [buf][o][j] 18 KB
  __shared__ __align__(16) unsigned short Pts[2][32][72];  // [buf][i][j]  9 KB
  __shared__ float e2row[NN];                              // 8 KB
  __shared__ float ls[32];

  const int t = threadIdx.x, lane = t & 63, w = t >> 6;
  const int q = lane >> 4, l15 = lane & 15;
  const int b = blockIdx.y;
  const int i0 = blockIdx.x * 32;
  const size_t bN = (size_t)b * NN;

  // stage the full e2 row for this batch (read every chunk)
  #pragma unroll
  for (int k = 0; k < 2; ++k) {
    const int idx = (t + 256 * k) * 4;
    *(f4v*)&e2row[idx] = *(const f4v*)&e2g[bN + idx];
  }

  const int iP = t >> 3, ocP = t & 7;          // P-gen: row iP, j-octet ocP
  const float e1v = e1g[bN + i0 + iP];
  const unsigned* arow = adjw + (size_t)(i0 + iP) * (NN / 32);

  f4v acc0 = {0.f, 0.f, 0.f, 0.f}, acc1 = {0.f, 0.f, 0.f, 0.f};
  float psum = 0.f;
  s8v whr0, whr1;

  auto prefetch = [&](int jt) {
    const int j0 = jt * 64;
    const int o0 = t >> 3, j80 = t & 7;
    whr0 = *(const s8v*)(whtg + (size_t)(b * 64 + o0) * NN + j0 + j80 * 8);
    const int i1 = t + 256, o1 = i1 >> 3, j81 = i1 & 7;
    whr1 = *(const s8v*)(whtg + (size_t)(b * 64 + o1) * NN + j0 + j81 * 8);
  };

  auto stage = [&](int buf, int jt) {
    const int j0 = jt * 64;
    { const int o = t >> 3, j8 = t & 7; *(s8v*)&Whs[buf][o][j8 * 8] = whr0; }
    { const int i1 = t + 256, o = i1 >> 3, j8 = i1 & 7; *(s8v*)&Whs[buf][o][j8 * 8] = whr1; }
    const unsigned wb = arow[(j0 >> 5) + (ocP >> 2)] >> ((ocP & 3) * 8);
    s8v prow;
    #pragma unroll
    for (int jj = 0; jj < 8; ++jj) {
      const float s = e1v + e2row[j0 + ocP * 8 + jj];
      const float lr = fmaxf(s, ALPHA * s);          // leaky_relu
      const float p = ((wb >> jj) & 1u) ? __expf(lr) : 0.f;
      psum += p;
      prow[jj] = (short)bf16rne(p);
    }
    *(s8v*)&Pts[buf][iP][ocP * 8] = prow;
  };

  prefetch(0);
  __syncthreads();            // e2row visible
  stage(0, 0);
  __syncthreads();

  for (int jt = 0; jt < 32; ++jt) {
    const int cur = jt & 1;
    if (jt < 31) prefetch(jt + 1);
    #pragma unroll
    for (int ks = 0; ks < 2; ++ks) {
      const s8v bfr = *(const s8v*)&Whs[cur][w * 16 + l15][ks * 32 + q * 8];
      const s8v af0 = *(const s8v*)&Pts[cur][l15][ks * 32 + q * 8];
      const s8v af1 = *(const s8v*)&Pts[cur][16 + l15][ks * 32 + q * 8];
      acc0 = __builtin_amdgcn_mfma_f32_16x16x32_bf16(af0, bfr, acc0, 0, 0, 0);
      acc1 = __builtin_amdgcn_mfma_f32_16x16x32_bf16(af1, bfr, acc1, 0, 0, 0);
    }
    if (jt < 31) stage(cur ^ 1, jt + 1);
    __syncthreads();
  }

  // row sums: thread partial covers fixed (iP, ocP) across all chunks
  psum += __shfl_xor(psum, 1);
  psum += __shfl_xor(psum, 2);
  psum += __shfl_xor(psum, 4);
  if (ocP == 0) ls[iP] = psum;
  __syncthreads();

  // epilogue: C/D layout col=lane&15, row=quad*4+reg (m89-verified)
  #pragma unroll
  for (int m = 0; m < 2; ++m) {
    const f4v av = m ? acc1 : acc0;
    #pragma unroll
    for (int r = 0; r < 4; ++r) {
      const int il = m * 16 + q * 4 + r;
      float v = av[r] / ls[il];
      v = v > 0.f ? v : expm1f(v);
      out[(bN + i0 + il) * 64 + w * 16 + l15] = v;
    }
  }
}

extern "C" void kernel_launch(void* const* d_in, const int* in_sizes, int n_in,
                              void* d_out, int out_size, void* d_ws, size_t ws_size,
                              hipStream_t stream) {
  (void)in_sizes; (void)n_in; (void)out_size; (void)ws_size;
  const float* h   = (const float*)d_in[0];
  const float* adj = (const float*)d_in[1];
  const float* W   = (const float*)d_in[2];
  const float* a   = (const float*)d_in[3];
  float* outp = (float*)d_out;

  // workspace carve: whtg 2 MB | e1 64 KB | e2 64 KB | adjw 512 KB
  unsigned short* whtg = (unsigned short*)d_ws;
  float* e1 = (float*)((char*)d_ws + (size_t)BB * 64 * NN * 2);
  float* e2 = e1 + (size_t)BB * NN;
  unsigned* adjw = (unsigned*)(e2 + (size_t)BB * NN);

  k_adj<<<NN, 256, 0, stream>>>(adj, adjw);
  k_wh<<<(BB * NN) / 64, 256, 0, stream>>>(h, W, a, whtg, e1, e2);
  k_attn<<<dim3(NN / 32, BB), 256, 0, stream>>>(adjw, whtg, e1, e2, outp);
}